// Round 8
// baseline (121.580 us; speedup 1.0000x reference)
//
#include <hip/hip_runtime.h>
#include <math.h>

#define NEI 15
#define ROWSTRIDE 16     // pad neighbor rows to 16 ints for int4 loads
#define MAXB_FUSED 1024  // co-residency guarantee from __launch_bounds__(256,4)

typedef float f4 __attribute__((ext_vector_type(4)));

// Compile-time component select from 4 int4s (K must be a constant after unroll)
#define GET16(n0, n1, n2, n3, K)                                   \
    ((K) < 8                                                       \
         ? ((K) < 4                                                \
                ? ((K) == 0 ? (n0).x : (K) == 1 ? (n0).y           \
                                : (K) == 2 ? (n0).z : (n0).w)      \
                : ((K) == 4 ? (n1).x : (K) == 5 ? (n1).y           \
                                : (K) == 6 ? (n1).z : (n1).w))     \
         : ((K) < 12                                               \
                ? ((K) == 8 ? (n2).x : (K) == 9 ? (n2).y           \
                                : (K) == 10 ? (n2).z : (n2).w)     \
                : ((K) == 12 ? (n3).x : (K) == 13 ? (n3).y         \
                                : (K) == 14 ? (n3).z : (n3).w)))

__device__ __forceinline__ int mbcnt64(unsigned long long m) {
    int c = __builtin_amdgcn_mbcnt_lo((unsigned)m, 0);
    c = __builtin_amdgcn_mbcnt_hi((unsigned)(m >> 32), c);
    return c;   // popcount of m over lanes strictly below this lane
}

// ---------------------------------------------------------------------------
// Kernel 1: grid-strided waves over rows; 4 nontemporal float4 loads (4 KB)
// in flight per iteration; single combined ballot skips all-zero chunks.
// Block 0 zeroes the arrival counter for the fused tail (stream-ordered).
// ---------------------------------------------------------------------------
__global__ void find_nb_kernel(const float* __restrict__ A,
                               int* __restrict__ nb,
                               int* __restrict__ arrivals,
                               int N, int totalWaves) {
    if (blockIdx.x == 0 && threadIdx.x == 0) *arrivals = 0;
    const int wavesPerBlock = blockDim.x >> 6;
    const int waveId = blockIdx.x * wavesPerBlock + (threadIdx.x >> 6);
    const int lane = threadIdx.x & 63;
    const int n4 = N >> 2;

    for (int row = waveId; row < N; row += totalWaves) {
        const f4* rowp = reinterpret_cast<const f4*>(A + (long long)row * N);
        int count = 0;

        for (int c0 = 0; c0 < n4; c0 += 256) {
            const int i0 = c0 + lane;
            const int i1 = i0 + 64, i2 = i0 + 128, i3 = i0 + 192;
            f4 v0 = {0.f, 0.f, 0.f, 0.f}, v1 = {0.f, 0.f, 0.f, 0.f};
            f4 v2 = {0.f, 0.f, 0.f, 0.f}, v3 = {0.f, 0.f, 0.f, 0.f};
            if (i0 < n4) v0 = __builtin_nontemporal_load(&rowp[i0]);
            if (i1 < n4) v1 = __builtin_nontemporal_load(&rowp[i1]);
            if (i2 < n4) v2 = __builtin_nontemporal_load(&rowp[i2]);
            if (i3 < n4) v3 = __builtin_nontemporal_load(&rowp[i3]);

            const bool a0 = (v0.x != 0.f) || (v0.y != 0.f) || (v0.z != 0.f) || (v0.w != 0.f);
            const bool a1 = (v1.x != 0.f) || (v1.y != 0.f) || (v1.z != 0.f) || (v1.w != 0.f);
            const bool a2 = (v2.x != 0.f) || (v2.y != 0.f) || (v2.z != 0.f) || (v2.w != 0.f);
            const bool a3 = (v3.x != 0.f) || (v3.y != 0.f) || (v3.z != 0.f) || (v3.w != 0.f);
            if (__ballot(a0 || a1 || a2 || a3) == 0ull) continue;   // common path

            #pragma unroll
            for (int q = 0; q < 4; ++q) {
                const f4 v = (q == 0) ? v0 : (q == 1) ? v1 : (q == 2) ? v2 : v3;
                const int idx = c0 + q * 64 + lane;
                const unsigned long long m0 = __ballot(v.x != 0.f);
                const unsigned long long m1 = __ballot(v.y != 0.f);
                const unsigned long long m2 = __ballot(v.z != 0.f);
                const unsigned long long m3 = __ballot(v.w != 0.f);
                if ((m0 | m1 | m2 | m3) != 0ull) {
                    const int below = mbcnt64(m0) + mbcnt64(m1) + mbcnt64(m2) + mbcnt64(m3);
                    const int b0 = (int)((m0 >> lane) & 1ull);
                    const int b1 = (int)((m1 >> lane) & 1ull);
                    const int b2 = (int)((m2 >> lane) & 1ull);
                    const int base = count + below;
                    if (v.x != 0.f) { const int p = base;                if (p < NEI) nb[row * ROWSTRIDE + p] = (idx << 2) + 0; }
                    if (v.y != 0.f) { const int p = base + b0;           if (p < NEI) nb[row * ROWSTRIDE + p] = (idx << 2) + 1; }
                    if (v.z != 0.f) { const int p = base + b0 + b1;      if (p < NEI) nb[row * ROWSTRIDE + p] = (idx << 2) + 2; }
                    if (v.w != 0.f) { const int p = base + b0 + b1 + b2; if (p < NEI) nb[row * ROWSTRIDE + p] = (idx << 2) + 3; }
                    count += __popcll(m0) + __popcll(m1) + __popcll(m2) + __popcll(m3);
                }
            }
        }
        // tail columns if N % 4 != 0
        const int base4 = n4 << 2;
        const int rem = N - base4;
        if (rem > 0) {
            float v = 0.f;
            if (lane < rem) v = A[(long long)row * N + base4 + lane];
            const unsigned long long m = __ballot(v != 0.f);
            if (v != 0.f) {
                const int p = count + mbcnt64(m);
                if (p < NEI) nb[row * ROWSTRIDE + p] = base4 + lane;
            }
        }
    }
}

// ---------------------------------------------------------------------------
// Kernel 2 (fused tail): count + block scan -> single arrive/release barrier
// (no per-block chains; only thread 0 spins, with s_sleep backoff) -> each
// block reduces its prefix from L2-hot blockSums -> emit from registers.
// masks/fragments never touch memory. Requires all B blocks co-resident
// (B <= MAXB_FUSED, guaranteed by __launch_bounds__(256,4)).
// ---------------------------------------------------------------------------
__global__ __launch_bounds__(256, 4) void tri_fused_kernel(
        const int* __restrict__ nb,
        int* blockSums, int* arrivals,
        int* __restrict__ out, int N, int B) {
    __shared__ int partial[256];
    const int tid = blockIdx.x * 256 + threadIdx.x;
    const int M = N * NEI;

    // ---- phase 1: count + mask (registers) ----
    int c = 0, mask = 0, i = 0, j = 0, a = 0;
    int4 w0 = {0,0,0,0}, w1 = {0,0,0,0}, w2 = {0,0,0,0}, w3 = {0,0,0,0};
    if (tid < M) {
        i = tid / NEI;
        j = tid - i * NEI;
        a = nb[i * ROWSTRIDE + j];
        if (a > i) {
            const int4* np = reinterpret_cast<const int4*>(nb + a * ROWSTRIDE);
            const int4 n0 = np[0], n1 = np[1], n2 = np[2], n3 = np[3];
            const int4* vp = reinterpret_cast<const int4*>(nb + i * ROWSTRIDE);
            w0 = vp[0]; w1 = vp[1]; w2 = vp[2]; w3 = vp[3];
            #pragma unroll
            for (int k = 1; k < NEI; ++k) {
                if (k > j) {
                    const int b = GET16(w0, w1, w2, w3, k);
                    const bool adj =
                        (n0.x == b) || (n0.y == b) || (n0.z == b) || (n0.w == b) ||
                        (n1.x == b) || (n1.y == b) || (n1.z == b) || (n1.w == b) ||
                        (n2.x == b) || (n2.y == b) || (n2.z == b) || (n2.w == b) ||
                        (n3.x == b) || (n3.y == b) || (n3.z == b);
                    if (adj) { mask |= (1 << k); ++c; }
                }
            }
        }
    }

    // ---- block-local exclusive scan ----
    partial[threadIdx.x] = c;
    __syncthreads();
    #pragma unroll
    for (int d = 1; d < 256; d <<= 1) {
        const int mine  = partial[threadIdx.x];
        const int other = (threadIdx.x >= d) ? partial[threadIdx.x - d] : 0;
        __syncthreads();
        partial[threadIdx.x] = mine + other;
        __syncthreads();
    }
    const int localExcl  = (threadIdx.x == 0) ? 0 : partial[threadIdx.x - 1];
    const int blockTotal = partial[255];

    // ---- single global barrier: publish, arrive, wait-all ----
    if (threadIdx.x == 0) {
        blockSums[blockIdx.x] = blockTotal;
        __threadfence();                       // make blockSums visible device-wide
        atomicAdd(arrivals, 1);                // device-scope by default
        while (__hip_atomic_load(arrivals, __ATOMIC_ACQUIRE,
                                 __HIP_MEMORY_SCOPE_AGENT) < B)
            __builtin_amdgcn_s_sleep(16);      // backoff: no L2 hammering
    }
    __syncthreads();

    // ---- prefix = sum of previous block totals (parallel, L2-hot) ----
    int s = 0;
    for (int idx = threadIdx.x; idx < blockIdx.x; idx += 256) s += blockSums[idx];
    partial[threadIdx.x] = s;
    __syncthreads();
    #pragma unroll
    for (int d = 128; d >= 1; d >>= 1) {
        if (threadIdx.x < d) partial[threadIdx.x] += partial[threadIdx.x + d];
        __syncthreads();
    }
    const int blockOff = partial[0];

    // ---- emit from registers ----
    if (tid < M && mask != 0) {
        int pos = blockOff + localExcl;
        #pragma unroll
        for (int k = 1; k < NEI; ++k) {
            if ((mask >> k) & 1) {
                const int b = GET16(w0, w1, w2, w3, k);
                out[3 * pos + 0] = i;
                out[3 * pos + 1] = a;
                out[3 * pos + 2] = b;
                ++pos;
            }
        }
    }
}

// ---------------------------------------------------------------------------
// Fallback kernels (unfused path, used only if B > MAXB_FUSED): identical to
// the verified R7 structure.
// ---------------------------------------------------------------------------
__global__ void count_tri_kernel(const int* __restrict__ nb,
                                 int* __restrict__ mask2,
                                 int* __restrict__ offs2,
                                 int* __restrict__ blockSums, int N) {
    __shared__ int partial[256];
    const int tid = blockIdx.x * 256 + threadIdx.x;
    const int M = N * NEI;
    int c = 0, mask = 0;
    if (tid < M) {
        const int i = tid / NEI;
        const int j = tid - i * NEI;
        const int a = nb[i * ROWSTRIDE + j];
        if (a > i) {
            const int4* np = reinterpret_cast<const int4*>(nb + a * ROWSTRIDE);
            const int4 n0 = np[0], n1 = np[1], n2 = np[2], n3 = np[3];
            const int4* vp = reinterpret_cast<const int4*>(nb + i * ROWSTRIDE);
            const int4 w0 = vp[0], w1 = vp[1], w2 = vp[2], w3 = vp[3];
            #pragma unroll
            for (int k = 1; k < NEI; ++k) {
                if (k > j) {
                    const int b = GET16(w0, w1, w2, w3, k);
                    const bool adj =
                        (n0.x == b) || (n0.y == b) || (n0.z == b) || (n0.w == b) ||
                        (n1.x == b) || (n1.y == b) || (n1.z == b) || (n1.w == b) ||
                        (n2.x == b) || (n2.y == b) || (n2.z == b) || (n2.w == b) ||
                        (n3.x == b) || (n3.y == b) || (n3.z == b);
                    if (adj) { mask |= (1 << k); ++c; }
                }
            }
        }
        mask2[tid] = mask;
    }
    partial[threadIdx.x] = c;
    __syncthreads();
    #pragma unroll
    for (int d = 1; d < 256; d <<= 1) {
        const int mine  = partial[threadIdx.x];
        const int other = (threadIdx.x >= d) ? partial[threadIdx.x - d] : 0;
        __syncthreads();
        partial[threadIdx.x] = mine + other;
        __syncthreads();
    }
    if (tid < M) offs2[tid] = (threadIdx.x == 0) ? 0 : partial[threadIdx.x - 1];
    if (threadIdx.x == 255) blockSums[blockIdx.x] = partial[255];
}

__global__ __launch_bounds__(256) void emit_tri_kernel(const int* __restrict__ nb,
                                                       const int* __restrict__ mask2,
                                                       const int* __restrict__ offs2,
                                                       const int* __restrict__ blockSums,
                                                       int* __restrict__ out, int N) {
    __shared__ int red[256];
    const int tid = blockIdx.x * 256 + threadIdx.x;
    const int M = N * NEI;
    int s = 0;
    for (int idx = threadIdx.x; idx < blockIdx.x; idx += 256) s += blockSums[idx];
    red[threadIdx.x] = s;
    __syncthreads();
    #pragma unroll
    for (int d = 128; d >= 1; d >>= 1) {
        if (threadIdx.x < d) red[threadIdx.x] += red[threadIdx.x + d];
        __syncthreads();
    }
    const int blockOff = red[0];

    if (tid >= M) return;
    const int mask = mask2[tid];
    if (mask == 0) return;
    const int i = tid / NEI;
    const int j = tid - i * NEI;
    const int a = nb[i * ROWSTRIDE + j];
    const int4* vp = reinterpret_cast<const int4*>(nb + i * ROWSTRIDE);
    const int4 w0 = vp[0], w1 = vp[1], w2 = vp[2], w3 = vp[3];
    int pos = blockOff + offs2[tid];
    #pragma unroll
    for (int k = 1; k < NEI; ++k) {
        if ((mask >> k) & 1) {
            const int b = GET16(w0, w1, w2, w3, k);
            out[3 * pos + 0] = i;
            out[3 * pos + 1] = a;
            out[3 * pos + 2] = b;
            ++pos;
        }
    }
}

extern "C" void kernel_launch(void* const* d_in, const int* in_sizes, int n_in,
                              void* d_out, int out_size, void* d_ws, size_t ws_size,
                              hipStream_t stream) {
    const float* A = (const float*)d_in[0];
    const long long total = (long long)in_sizes[0];
    const int N = (int)llround(sqrt((double)total));
    const int M = N * NEI;
    const int B = (M + 255) / 256;              // tail blocks

    int* ws = (int*)d_ws;
    // Workspace (ints): nb[N*16] | blockSums[B] | arrivals[1] | (fallback: mask2[M] | offs2[M])
    int* w_nb    = ws;
    int* w_bsum  = ws + N * ROWSTRIDE;
    int* w_arr   = w_bsum + B;
    int* w_mask2 = w_arr + 1;
    int* w_offs2 = w_mask2 + M;

    int* out = (int*)d_out;

    // 1) find neighbors (written already sorted ascending) + zero arrival ctr.
    {
        int totalWaves = (N <= 8192) ? N : (N + 1) / 2;
        const int blocks = (totalWaves + 3) / 4;
        totalWaves = blocks * 4;
        find_nb_kernel<<<blocks, 256, 0, stream>>>(A, w_nb, w_arr, N, totalWaves);
    }
    if (B <= MAXB_FUSED) {
        // 2) fused count + barrier + emit (all blocks co-resident)
        tri_fused_kernel<<<B, 256, 0, stream>>>(w_nb, w_bsum, w_arr, out, N, B);
    } else {
        // fallback: unfused 3-dispatch path
        count_tri_kernel<<<B, 256, 0, stream>>>(w_nb, w_mask2, w_offs2, w_bsum, N);
        emit_tri_kernel<<<B, 256, 0, stream>>>(w_nb, w_mask2, w_offs2, w_bsum, out, N);
    }
}

// Round 9
// 75.510 us; speedup vs baseline: 1.6101x; 1.6101x over previous
//
#include <hip/hip_runtime.h>
#include <math.h>

#define NEI 15
#define ROWSTRIDE 16     // pad neighbor rows to 16 ints for int4 loads

typedef float f4 __attribute__((ext_vector_type(4)));

// Compile-time component select from 4 int4s (K must be a constant after unroll)
#define GET16(n0, n1, n2, n3, K)                                   \
    ((K) < 8                                                       \
         ? ((K) < 4                                                \
                ? ((K) == 0 ? (n0).x : (K) == 1 ? (n0).y           \
                                : (K) == 2 ? (n0).z : (n0).w)      \
                : ((K) == 4 ? (n1).x : (K) == 5 ? (n1).y           \
                                : (K) == 6 ? (n1).z : (n1).w))     \
         : ((K) < 12                                               \
                ? ((K) == 8 ? (n2).x : (K) == 9 ? (n2).y           \
                                : (K) == 10 ? (n2).z : (n2).w)     \
                : ((K) == 12 ? (n3).x : (K) == 13 ? (n3).y         \
                                : (K) == 14 ? (n3).z : (n3).w)))

__device__ __forceinline__ int mbcnt64(unsigned long long m) {
    int c = __builtin_amdgcn_mbcnt_lo((unsigned)m, 0);
    c = __builtin_amdgcn_mbcnt_hi((unsigned)(m >> 32), c);
    return c;   // popcount of m over lanes strictly below this lane
}

// ---------------------------------------------------------------------------
// Kernel 1: grid-strided waves over rows; 4 nontemporal float4 loads (4 KB)
// in flight per iteration; single combined ballot skips all-zero chunks.
// Ballot + mbcnt ranking writes neighbors in ascending column order.
// Runs at ~6.15 TB/s on the mandatory 400 MB adjacency read (~97% of the
// 6.3 TB/s achievable ceiling).
// ---------------------------------------------------------------------------
__global__ void find_nb_kernel(const float* __restrict__ A,
                               int* __restrict__ nb, int N, int totalWaves) {
    const int wavesPerBlock = blockDim.x >> 6;
    const int waveId = blockIdx.x * wavesPerBlock + (threadIdx.x >> 6);
    const int lane = threadIdx.x & 63;
    const int n4 = N >> 2;

    for (int row = waveId; row < N; row += totalWaves) {
        const f4* rowp = reinterpret_cast<const f4*>(A + (long long)row * N);
        int count = 0;

        for (int c0 = 0; c0 < n4; c0 += 256) {
            const int i0 = c0 + lane;
            const int i1 = i0 + 64, i2 = i0 + 128, i3 = i0 + 192;
            f4 v0 = {0.f, 0.f, 0.f, 0.f}, v1 = {0.f, 0.f, 0.f, 0.f};
            f4 v2 = {0.f, 0.f, 0.f, 0.f}, v3 = {0.f, 0.f, 0.f, 0.f};
            if (i0 < n4) v0 = __builtin_nontemporal_load(&rowp[i0]);
            if (i1 < n4) v1 = __builtin_nontemporal_load(&rowp[i1]);
            if (i2 < n4) v2 = __builtin_nontemporal_load(&rowp[i2]);
            if (i3 < n4) v3 = __builtin_nontemporal_load(&rowp[i3]);

            const bool a0 = (v0.x != 0.f) || (v0.y != 0.f) || (v0.z != 0.f) || (v0.w != 0.f);
            const bool a1 = (v1.x != 0.f) || (v1.y != 0.f) || (v1.z != 0.f) || (v1.w != 0.f);
            const bool a2 = (v2.x != 0.f) || (v2.y != 0.f) || (v2.z != 0.f) || (v2.w != 0.f);
            const bool a3 = (v3.x != 0.f) || (v3.y != 0.f) || (v3.z != 0.f) || (v3.w != 0.f);
            if (__ballot(a0 || a1 || a2 || a3) == 0ull) continue;   // common path

            #pragma unroll
            for (int q = 0; q < 4; ++q) {
                const f4 v = (q == 0) ? v0 : (q == 1) ? v1 : (q == 2) ? v2 : v3;
                const int idx = c0 + q * 64 + lane;
                const unsigned long long m0 = __ballot(v.x != 0.f);
                const unsigned long long m1 = __ballot(v.y != 0.f);
                const unsigned long long m2 = __ballot(v.z != 0.f);
                const unsigned long long m3 = __ballot(v.w != 0.f);
                if ((m0 | m1 | m2 | m3) != 0ull) {
                    const int below = mbcnt64(m0) + mbcnt64(m1) + mbcnt64(m2) + mbcnt64(m3);
                    const int b0 = (int)((m0 >> lane) & 1ull);
                    const int b1 = (int)((m1 >> lane) & 1ull);
                    const int b2 = (int)((m2 >> lane) & 1ull);
                    const int base = count + below;
                    if (v.x != 0.f) { const int p = base;                if (p < NEI) nb[row * ROWSTRIDE + p] = (idx << 2) + 0; }
                    if (v.y != 0.f) { const int p = base + b0;           if (p < NEI) nb[row * ROWSTRIDE + p] = (idx << 2) + 1; }
                    if (v.z != 0.f) { const int p = base + b0 + b1;      if (p < NEI) nb[row * ROWSTRIDE + p] = (idx << 2) + 2; }
                    if (v.w != 0.f) { const int p = base + b0 + b1 + b2; if (p < NEI) nb[row * ROWSTRIDE + p] = (idx << 2) + 3; }
                    count += __popcll(m0) + __popcll(m1) + __popcll(m2) + __popcll(m3);
                }
            }
        }
        // tail columns if N % 4 != 0
        const int base4 = n4 << 2;
        const int rem = N - base4;
        if (rem > 0) {
            float v = 0.f;
            if (lane < rem) v = A[(long long)row * N + base4 + lane];
            const unsigned long long m = __ballot(v != 0.f);
            if (v != 0.f) {
                const int p = count + mbcnt64(m);
                if (p < NEI) nb[row * ROWSTRIDE + p] = base4 + lane;
            }
        }
    }
}

// ---------------------------------------------------------------------------
// Kernel 2: per-(i,j) triangle count + 15-bit adjacency mask, fused with the
// per-block (256-wide) exclusive scan. offs2 is block-local; blockSums[b] is
// the block total. No cross-block dependencies (R6/R8 showed any cross-block
// waiting costs 35-45 us on this chip).
// ---------------------------------------------------------------------------
__global__ void count_tri_kernel(const int* __restrict__ nb,
                                 int* __restrict__ mask2,
                                 int* __restrict__ offs2,
                                 int* __restrict__ blockSums, int N) {
    __shared__ int partial[256];
    const int tid = blockIdx.x * 256 + threadIdx.x;
    const int M = N * NEI;
    int c = 0, mask = 0;
    if (tid < M) {
        const int i = tid / NEI;
        const int j = tid - i * NEI;
        const int a = nb[i * ROWSTRIDE + j];
        if (a > i) {
            const int4* np = reinterpret_cast<const int4*>(nb + a * ROWSTRIDE);
            const int4 n0 = np[0], n1 = np[1], n2 = np[2], n3 = np[3];
            const int4* vp = reinterpret_cast<const int4*>(nb + i * ROWSTRIDE);
            const int4 w0 = vp[0], w1 = vp[1], w2 = vp[2], w3 = vp[3];
            #pragma unroll
            for (int k = 1; k < NEI; ++k) {
                if (k > j) {
                    const int b = GET16(w0, w1, w2, w3, k);
                    const bool adj =
                        (n0.x == b) || (n0.y == b) || (n0.z == b) || (n0.w == b) ||
                        (n1.x == b) || (n1.y == b) || (n1.z == b) || (n1.w == b) ||
                        (n2.x == b) || (n2.y == b) || (n2.z == b) || (n2.w == b) ||
                        (n3.x == b) || (n3.y == b) || (n3.z == b);
                    if (adj) { mask |= (1 << k); ++c; }
                }
            }
        }
        mask2[tid] = mask;
    }
    partial[threadIdx.x] = c;
    __syncthreads();
    #pragma unroll
    for (int d = 1; d < 256; d <<= 1) {
        const int mine  = partial[threadIdx.x];
        const int other = (threadIdx.x >= d) ? partial[threadIdx.x - d] : 0;
        __syncthreads();
        partial[threadIdx.x] = mine + other;
        __syncthreads();
    }
    if (tid < M) offs2[tid] = (threadIdx.x == 0) ? 0 : partial[threadIdx.x - 1];
    if (threadIdx.x == 255) blockSums[blockIdx.x] = partial[255];
}

// ---------------------------------------------------------------------------
// Kernel 3: emit. Each block first reduces blockSums[0..blockIdx) itself
// (<=586 L2-hot ints, LDS tree reduce) -- no serial scan dispatch.
// Then decodes masks. Global order (i asc, j asc, k asc) == lexicographic.
// ---------------------------------------------------------------------------
__global__ __launch_bounds__(256) void emit_tri_kernel(const int* __restrict__ nb,
                                                       const int* __restrict__ mask2,
                                                       const int* __restrict__ offs2,
                                                       const int* __restrict__ blockSums,
                                                       int* __restrict__ out, int N) {
    __shared__ int red[256];
    const int tid = blockIdx.x * 256 + threadIdx.x;
    const int M = N * NEI;

    // block offset = sum of all previous block totals
    int s = 0;
    for (int idx = threadIdx.x; idx < blockIdx.x; idx += 256) s += blockSums[idx];
    red[threadIdx.x] = s;
    __syncthreads();
    #pragma unroll
    for (int d = 128; d >= 1; d >>= 1) {
        if (threadIdx.x < d) red[threadIdx.x] += red[threadIdx.x + d];
        __syncthreads();
    }
    const int blockOff = red[0];

    if (tid >= M) return;
    const int mask = mask2[tid];
    if (mask == 0) return;
    const int i = tid / NEI;
    const int j = tid - i * NEI;
    const int a = nb[i * ROWSTRIDE + j];
    const int4* vp = reinterpret_cast<const int4*>(nb + i * ROWSTRIDE);
    const int4 w0 = vp[0], w1 = vp[1], w2 = vp[2], w3 = vp[3];
    int pos = blockOff + offs2[tid];
    #pragma unroll
    for (int k = 1; k < NEI; ++k) {
        if ((mask >> k) & 1) {
            const int b = GET16(w0, w1, w2, w3, k);
            out[3 * pos + 0] = i;
            out[3 * pos + 1] = a;
            out[3 * pos + 2] = b;
            ++pos;
        }
    }
}

extern "C" void kernel_launch(void* const* d_in, const int* in_sizes, int n_in,
                              void* d_out, int out_size, void* d_ws, size_t ws_size,
                              hipStream_t stream) {
    const float* A = (const float*)d_in[0];
    const long long total = (long long)in_sizes[0];
    const int N = (int)llround(sqrt((double)total));
    const int M = N * NEI;
    const int B = (M + 255) / 256;              // count/emit blocks

    int* ws = (int*)d_ws;
    // Workspace (ints): nb[N*16] | mask2[M] | offs2[M] | blockSums[B]
    int* w_nb    = ws;
    int* w_mask2 = ws + N * ROWSTRIDE;
    int* w_offs2 = w_mask2 + M;
    int* w_bsum  = w_offs2 + M;

    int* out = (int*)d_out;

    // 1) find neighbors (written already sorted ascending). Balanced grid:
    //    each wave handles an equal number of rows, all blocks resident.
    {
        int totalWaves = (N <= 8192) ? N : (N + 1) / 2;
        const int blocks = (totalWaves + 3) / 4;
        totalWaves = blocks * 4;
        find_nb_kernel<<<blocks, 256, 0, stream>>>(A, w_nb, N, totalWaves);
    }
    // 2) count per (i,j) + adjacency masks + fused per-block scan
    count_tri_kernel<<<B, 256, 0, stream>>>(w_nb, w_mask2, w_offs2, w_bsum, N);
    // 3) emit (per-block offset reduced in-kernel; no serial scan dispatch)
    emit_tri_kernel<<<B, 256, 0, stream>>>(w_nb, w_mask2, w_offs2, w_bsum, out, N);
}